// Round 14
// baseline (111.720 us; speedup 1.0000x reference)
//
#include <hip/hip_runtime.h>

// MultiheadAttention: B=2, S=2048, D=1024, H=16, DH=64, NF=4
// Pipeline (5 kernels):
//   1. prep: x->bf16, Wq|Wk|Wv->bf16, Weff=sum w[f]*Wout[f]->bf16, beff
//   2. qkv = x @ Wqkv^T + b   (256x256 tile, 8 waves, 3-slab counted-vmcnt
//      pipeline with 4-phase T3 interleave: per phase {ds_read, 1 stage load,
//      s_barrier, lgkmcnt(0), 8 MFMA, s_barrier}; raw s_barrier keeps vmcnt
//      un-drained across phases; q pre-scaled log2e/8; v written transposed)
//   3. flash attention v8: XCD-local grid, paired q-tiles, split-KV,
//      swapped QK^T, defer-max
//   4. combine split partials (rows 1024..2047 per bh)
//   5. out = attn @ Weff^T + beff  (128x128, 3-buffer pipeline)
typedef unsigned short u16;
typedef __bf16 bf16_t;
typedef bf16_t bf16x8 __attribute__((ext_vector_type(8)));
typedef bf16_t bf16x4 __attribute__((ext_vector_type(4)));
typedef float f32x4 __attribute__((ext_vector_type(4)));
typedef u16 u16x8 __attribute__((ext_vector_type(8)));
typedef u16 u16x4 __attribute__((ext_vector_type(4)));

#define DEV __device__ __forceinline__

DEV u16 f2bf(float f) {  // round-to-nearest-even f32 -> bf16
  unsigned u = __float_as_uint(f);
  u += 0x7FFFu + ((u >> 16) & 1u);
  return (u16)(u >> 16);
}

DEV void async_ld16(const void* g, void* lds_wave_uniform) {
  // dst is wave-uniform base; HW writes base + lane*16. Global src is per-lane.
  __builtin_amdgcn_global_load_lds(
      (const __attribute__((address_space(1))) void*)g,
      (__attribute__((address_space(3))) void*)lds_wave_uniform, 16, 0, 0);
}

// row-swizzle for 64B LDS rows (4 x 16B chunks)
DEV int KF(int r) { return (r & 3) ^ ((r >> 2) & 1); }

// ---------------- fused prep: cvt x, cvt W's, build Weff/beff ----------------
__global__ __launch_bounds__(256) void prep_kernel(
    const float* __restrict__ x, const float* __restrict__ Wq,
    const float* __restrict__ Wk, const float* __restrict__ Wv,
    const float* __restrict__ w4, const float* __restrict__ Wout,
    const float* __restrict__ bout, u16* __restrict__ xbf,
    u16* __restrict__ wqkv, u16* __restrict__ Weff, float* __restrict__ beff) {
  constexpr int NX = 1048576;            // x float4s
  constexpr int NW = 262144;             // per-W float4s
  const int stride = gridDim.x * 256;
  for (int id = blockIdx.x * 256 + threadIdx.x; id < NX + 3 * NW + NW;
       id += stride) {
    if (id < NX) {
      const float4 v = ((const float4*)x)[id];
      u16x4 o;
      o[0] = f2bf(v.x); o[1] = f2bf(v.y); o[2] = f2bf(v.z); o[3] = f2bf(v.w);
      ((u16x4*)xbf)[id] = o;
    } else if (id < NX + 3 * NW) {
      const int wi = id - NX;
      const int which = wi >> 18, j = wi & (NW - 1);
      const float* src = which == 0 ? Wq : (which == 1 ? Wk : Wv);
      const float4 v = ((const float4*)src)[j];
      u16x4 o;
      o[0] = f2bf(v.x); o[1] = f2bf(v.y); o[2] = f2bf(v.z); o[3] = f2bf(v.w);
      ((u16x4*)wqkv)[wi] = o;
    } else {
      const int i = id - NX - 3 * NW;
      const float w0 = w4[0], w1 = w4[1], w2 = w4[2], w3 = w4[3];
      const float4* W = (const float4*)Wout;
      const float4 a = W[i], b1 = W[NW + i], b2 = W[2 * NW + i],
                   b3 = W[3 * NW + i];
      u16x4 o;
      o[0] = f2bf(w0 * a.x + w1 * b1.x + w2 * b2.x + w3 * b3.x);
      o[1] = f2bf(w0 * a.y + w1 * b1.y + w2 * b2.y + w3 * b3.y);
      o[2] = f2bf(w0 * a.z + w1 * b1.z + w2 * b2.z + w3 * b3.z);
      o[3] = f2bf(w0 * a.w + w1 * b1.w + w2 * b2.w + w3 * b3.w);
      ((u16x4*)Weff)[i] = o;
      if (i < 256) {
        const float4* B4 = (const float4*)bout;
        const float4 ba = B4[i], c1 = B4[256 + i], c2 = B4[512 + i],
                     c3 = B4[768 + i];
        float4 ob;
        ob.x = w0 * ba.x + w1 * c1.x + w2 * c2.x + w3 * c3.x;
        ob.y = w0 * ba.y + w1 * c1.y + w2 * c2.y + w3 * c3.y;
        ob.z = w0 * ba.z + w1 * c1.z + w2 * c2.z + w3 * c3.z;
        ob.w = w0 * ba.w + w1 * c1.w + w2 * c2.w + w3 * c3.w;
        ((float4*)beff)[i] = ob;
      }
    }
  }
}

// ======== GEMM core: 128x128 tile, BK=32, 3-buffer counted-vmcnt pipeline ===
#define GEMM_PIPELINE_LOOP(A_, B_, m0_, n0_, K_)                               \
  int rA[2], oA[2], dstc[2];                                                   \
  _Pragma("unroll") for (int j = 0; j < 2; ++j) {                              \
    const int c = (j * 4 + w) * 64 + lane;                                     \
    rA[j] = c >> 2;                                                            \
    oA[j] = ((c & 3) ^ KF(rA[j])) * 8;                                         \
    dstc[j] = (j * 4 + w) * 512;                                               \
  }                                                                            \
  auto stage = [&](int buf, int kt) {                                          \
    _Pragma("unroll") for (int j = 0; j < 2; ++j) {                            \
      async_ld16(A_ + (m0_ + rA[j]) * K_ + kt + oA[j],                         \
                 &LDS[buf * 4096 + dstc[j]]);                                  \
      async_ld16(B_ + (n0_ + rA[j]) * K_ + kt + oA[j],                         \
                 &LDS[12288 + buf * 4096 + dstc[j]]);                          \
    }                                                                          \
  };                                                                           \
  f32x4 acc[4][4] = {};                                                        \
  stage(0, 0);                                                                 \
  stage(1, 32);                                                                \
  const int nt = K_ / 32;                                                      \
  int cur = 0, stg = 2;                                                        \
  for (int t = 0; t < nt; ++t) {                                               \
    if (t == nt - 1)                                                           \
      asm volatile("s_waitcnt vmcnt(0)\ns_barrier" ::: "memory");              \
    else                                                                       \
      asm volatile("s_waitcnt vmcnt(4)\ns_barrier" ::: "memory");              \
    __builtin_amdgcn_sched_barrier(0);                                         \
    if (t + 2 < nt) stage(stg, (t + 2) * 32);                                  \
    bf16x8 af[4], bfr[4];                                                      \
    _Pragma("unroll") for (int i = 0; i < 4; ++i) {                            \
      const int ra = wr * 64 + i * 16 + l15;                                   \
      const int rb = wc * 64 + i * 16 + l15;                                   \
      af[i] = *(const bf16x8*)&LDS[cur * 4096 + ra * 32 + ((l4 ^ KF(ra)) * 8)];\
      bfr[i] = *(const bf16x8*)&LDS[12288 + cur * 4096 + rb * 32 +             \
                                    ((l4 ^ KF(rb)) * 8)];                      \
    }                                                                          \
    __builtin_amdgcn_s_setprio(1);                                             \
    _Pragma("unroll") for (int i = 0; i < 4; ++i)                              \
        _Pragma("unroll") for (int j = 0; j < 4; ++j)                          \
            acc[i][j] = __builtin_amdgcn_mfma_f32_16x16x32_bf16(               \
                af[i], bfr[j], acc[i][j], 0, 0, 0);                            \
    __builtin_amdgcn_s_setprio(0);                                             \
    cur = cur == 2 ? 0 : cur + 1;                                              \
    stg = stg == 2 ? 0 : stg + 1;                                              \
  }

// ---------------- out GEMM: C[M,N](f32) = A @ Bw^T + bias ----------------
__global__ __launch_bounds__(256) void gemm_bt_kernel(
    const u16* __restrict__ A, const u16* __restrict__ Bw,
    const float* __restrict__ bias, float* __restrict__ C, int M, int N, int K) {
  __shared__ u16 LDS[24576];
  const int tid = threadIdx.x;
  const int w = tid >> 6, lane = tid & 63;
  const int l15 = lane & 15, l4 = lane >> 4;
  const int wr = w >> 1, wc = w & 1;
  const long m0 = (long)blockIdx.y * 128, n0 = (long)blockIdx.x * 128;

  GEMM_PIPELINE_LOOP(A, Bw, m0, n0, K)

#pragma unroll
  for (int i = 0; i < 4; ++i) {
    const long row0 = m0 + wr * 64 + i * 16 + l4 * 4;
#pragma unroll
    for (int j = 0; j < 4; ++j) {
      const long col = n0 + wc * 64 + j * 16 + l15;
      const float bb = bias[col];
#pragma unroll
      for (int r = 0; r < 4; ++r)
        C[(row0 + r) * N + col] = acc[i][j][r] + bb;
    }
  }
}

// -------- fused QKV GEMM v3: 256x256, 8 waves, 3-slab, 4-phase interleave ---
// grid (12,16). Slab rotation: K-tile t lives in slab t%3; stage of tile t+2
// targets slab (t+2)%3 (never read concurrently -> race-free). Per K-step,
// 4 phases: {ds_read 2 A-frags (+4 B in ph0), 1 stage load, s_barrier,
// lgkmcnt(0), 8 MFMA, s_barrier}. Raw s_barrier (NOT __syncthreads) so the
// staging vmcnt queue is never drained mid-step; vmcnt(4) once per step tail.
__global__ __launch_bounds__(512) void gemm_qkv_kernel(
    const u16* __restrict__ A, const u16* __restrict__ Bw,
    const float* __restrict__ bq, const float* __restrict__ bk,
    const float* __restrict__ bv, u16* __restrict__ qo, u16* __restrict__ ko,
    u16* __restrict__ vt) {
  constexpr int K = 1024;
  __shared__ u16 LDS[49152];  // A slabs 3x8192 u16 @0; B slabs 3x8192 @24576
  const int tid = threadIdx.x;
  const int w = tid >> 6, lane = tid & 63;
  const int l15 = lane & 15, l4 = lane >> 4;
  const int wr = w >> 2, wc = w & 3;
  const long m0 = (long)blockIdx.y * 256, n0 = (long)blockIdx.x * 256;
  const int seg = blockIdx.x >> 2;  // 0=q 1=k 2=v
  const float* bias = seg == 0 ? bq : (seg == 1 ? bk : bv);
  const float scale = seg == 0 ? 0.18033688011112042f : 1.0f;  // log2e/8

  int rA[2], oA[2], dstc[2];
#pragma unroll
  for (int j = 0; j < 2; ++j) {
    const int c = (j * 8 + w) * 64 + lane;  // chunk id 0..1023
    rA[j] = c >> 2;                         // row 0..255
    oA[j] = ((c & 3) ^ KF(rA[j])) * 8;      // inverse-swizzled src col
    dstc[j] = (j * 8 + w) * 512;            // linear LDS dest (u16)
  }
  auto stageA = [&](int slab, int kt, int j) {
    async_ld16(A + (m0 + rA[j]) * K + kt + oA[j], &LDS[slab * 8192 + dstc[j]]);
  };
  auto stageB = [&](int slab, int kt, int j) {
    async_ld16(Bw + (n0 + rA[j]) * K + kt + oA[j],
               &LDS[24576 + slab * 8192 + dstc[j]]);
  };

  f32x4 acc[8][4] = {};
  // prologue: tiles 0 (slab0) and 1 (slab1); vmcnt(4) -> tile 0 landed
  stageA(0, 0, 0); stageA(0, 0, 1); stageB(0, 0, 0); stageB(0, 0, 1);
  stageA(1, 32, 0); stageA(1, 32, 1); stageB(1, 32, 0); stageB(1, 32, 1);
  asm volatile("s_waitcnt vmcnt(4)\ns_barrier" ::: "memory");

  const int nt = K / 32;  // 32
  for (int t = 0; t < nt; ++t) {
    const int s = t % 3;
    const int s2 = (t + 2) % 3;
    const int kt2 = (t + 2) * 32;
    const bool st = (t + 2) < nt;
    bf16x8 bfr[4];
#pragma unroll
    for (int ph = 0; ph < 4; ++ph) {
      // ---- phase reads: 2 A-frags (+ all 4 B-frags in phase 0) ----
      if (ph == 0) {
#pragma unroll
        for (int j = 0; j < 4; ++j) {
          const int rb = wc * 64 + j * 16 + l15;
          bfr[j] = *(const bf16x8*)&LDS[24576 + s * 8192 + rb * 32 +
                                        ((l4 ^ KF(rb)) * 8)];
        }
      }
      const int ra0 = wr * 128 + (2 * ph) * 16 + l15;
      const int ra1 = wr * 128 + (2 * ph + 1) * 16 + l15;
      const bf16x8 af0 =
          *(const bf16x8*)&LDS[s * 8192 + ra0 * 32 + ((l4 ^ KF(ra0)) * 8)];
      const bf16x8 af1 =
          *(const bf16x8*)&LDS[s * 8192 + ra1 * 32 + ((l4 ^ KF(ra1)) * 8)];
      // ---- one stage load per phase (tile t+2, untouched slab) ----
      if (st) {
        if (ph == 0) stageA(s2, kt2, 0);
        else if (ph == 1) stageA(s2, kt2, 1);
        else if (ph == 2) stageB(s2, kt2, 0);
        else stageB(s2, kt2, 1);
      }
      asm volatile("s_barrier" ::: "memory");
      asm volatile("s_waitcnt lgkmcnt(0)" ::: "memory");
      __builtin_amdgcn_s_setprio(1);
#pragma unroll
      for (int j = 0; j < 4; ++j) {
        acc[2 * ph][j] = __builtin_amdgcn_mfma_f32_16x16x32_bf16(
            af0, bfr[j], acc[2 * ph][j], 0, 0, 0);
        acc[2 * ph + 1][j] = __builtin_amdgcn_mfma_f32_16x16x32_bf16(
            af1, bfr[j], acc[2 * ph + 1][j], 0, 0, 0);
      }
      __builtin_amdgcn_s_setprio(0);
      if (ph < 3) asm volatile("s_barrier" ::: "memory");
    }
    // step tail: retire previous step's 4 loads (tile t+1 ready)
    if (t >= nt - 3)
      asm volatile("s_waitcnt vmcnt(0)\ns_barrier" ::: "memory");
    else
      asm volatile("s_waitcnt vmcnt(4)\ns_barrier" ::: "memory");
  }

  __syncthreads();  // staging LDS now free for epilogue tiles
  const long ccol0 = n0 - (long)seg * 1024;
  if (seg < 2) {
    // ---- q/k epilogue: two 256x128 halves, swizzled LDS -> u16x8 stores ----
    u16* outp = seg == 0 ? qo : ko;
#pragma unroll
    for (int h = 0; h < 2; ++h) {
      if ((wc >> 1) == h) {
#pragma unroll
        for (int i = 0; i < 8; ++i)
#pragma unroll
          for (int j = 0; j < 4; ++j) {
            const int colb = (wc & 1) * 64 + j * 16 + l15;  // 0..127
            const float bb = bias[ccol0 + h * 128 + colb];
#pragma unroll
            for (int r = 0; r < 4; ++r) {
              const int row = wr * 128 + i * 16 + l4 * 4 + r;
              LDS[row * 128 + (colb ^ ((row & 15) << 3))] =
                  f2bf((acc[i][j][r] + bb) * scale);
            }
          }
      }
      __syncthreads();
#pragma unroll
      for (int p = 0; p < 8; ++p) {
        const int cid = p * 512 + tid;
        const int row = cid >> 4, c = cid & 15;
        const u16x8 vch =
            *(const u16x8*)&LDS[row * 128 + ((c ^ (row & 15)) * 8)];
        *(u16x8*)&outp[(m0 + row) * 1024 + ccol0 + h * 128 + c * 8] = vch;
      }
      __syncthreads();
    }
  } else {
    // ---- v epilogue: two transposed 128x256 halves -> Vt[b,h,d,s] ----
    const int b = (int)(m0 >> 11);
    const int s0 = (int)(m0 & 2047);
#pragma unroll
    for (int h = 0; h < 2; ++h) {
      if ((wc >> 1) == h) {
#pragma unroll
        for (int i = 0; i < 8; ++i)
#pragma unroll
          for (int j = 0; j < 4; ++j) {
            const int colb = (wc & 1) * 64 + j * 16 + l15;  // 0..127
            const float bb = bias[ccol0 + h * 128 + colb];
#pragma unroll
            for (int r = 0; r < 4; ++r) {
              const int row = wr * 128 + i * 16 + l4 * 4 + r;  // 0..255
              LDS[colb * 256 + (row ^ ((colb & 15) << 3))] =
                  f2bf(acc[i][j][r] + bb);
            }
          }
      }
      __syncthreads();
#pragma unroll
      for (int p = 0; p < 8; ++p) {
        const int cid = p * 512 + tid;
        const int c = cid >> 5, r0 = (cid & 31) * 8;  // c 0..127, r0 0..248
        const u16x8 vch = *(const u16x8*)&LDS[c * 256 + (r0 ^ ((c & 15) << 3))];
        const int gcol = (int)ccol0 + h * 128 + c;  // 0..1023 within v
        const int hh = gcol >> 6, d = gcol & 63;
        *(u16x8*)&vt[(size_t)((b * 16 + hh) * 64 + d) * 2048 + s0 + r0] = vch;
      }
      __syncthreads();
    }
  }
}

// ---------------- causal flash attention v8 ----------------
// grid (32, 8): blockIdx.x = bh, blockIdx.y = xb. Linear block id =
// bh + 32*xb -> XCD = bh % 8: ALL 8 blocks of one bh land on the same XCD,
// so its K/V (512 KB) stays L2-resident (4 bh x 512 KB = 2 MB / 4 MB L2).
// xb: p = xb>>1, seg = xb&1. Macro q-tiles (256 rows) pair (p, 7-p):
//   seg0: tile p, kv 0..4p+3 (final) then tile 7-p, kv 0..13-4p (partial 0)
//   seg1: tile 7-p, kv 14-4p..31-4p (partial 1)
// Each block exactly 18 KV steps. Triple-buffered K/V, vmcnt(2) barriers.
// V-reads hoisted above softmax (P-independent, latency hides under exp2).
__global__ __launch_bounds__(512) void flash_kernel(
    const u16* __restrict__ Q, const u16* __restrict__ Kg,
    const u16* __restrict__ Vt, u16* __restrict__ O,
    u16* __restrict__ accP, float* __restrict__ mP, float* __restrict__ lP) {
  constexpr int S = 2048, D = 1024, DH = 64;
  __shared__ u16 Ks[3][4096];  // [key][feat], XOR-swizzled 16B chunks
  __shared__ u16 Vs[3][4096];  // [d][key]
  __shared__ u16 Ps[8][2048];  // per-wave 32q x 64key
  const int tid = threadIdx.x;
  const int w = tid >> 6, lane = tid & 63;
  const int l15 = lane & 15, l4 = lane >> 4;
  const int bh = blockIdx.x, b = bh >> 4, h = bh & 15;
  const int xb = blockIdx.y;
  const int p = xb >> 1, seg = xb & 1;
  const int p1len = seg ? 0 : 4 * p + 4;
  const int kvoff = seg ? (14 - 4 * p) : 0;
  const int TA = seg ? (7 - p) : p;
  const int TB = 7 - p;
  const int qbA_keep = TA * 256 + w * 32;  // for the mid-loop final flush

  const u16* Kbh = Kg + (size_t)b * S * D + h * DH;
  const u16* Vbh = Vt + (size_t)bh * DH * S;

  const int srow = tid >> 3;
  const int scol = ((tid & 7) ^ (srow & 7)) * 8;
  const int sw = l15 & 7;

  // Q fragments: working set qf (phase A) and preloaded qfB (phase B, seg0)
  bf16x8 qf[2][2], qfB[2][2];
#pragma unroll
  for (int c = 0; c < 2; ++c) {
    const u16* qp =
        Q + (size_t)(b * S + qbA_keep + c * 16 + l15) * D + h * DH + l4 * 8;
    qf[c][0] = *(const bf16x8*)qp;
    qf[c][1] = *(const bf16x8*)(qp + 32);
    qfB[c][0] = qf[c][0];
    qfB[c][1] = qf[c][1];
  }
  if (!seg) {
    const int qbB = TB * 256 + w * 32;
#pragma unroll
    for (int c = 0; c < 2; ++c) {
      const u16* qp =
          Q + (size_t)(b * S + qbB + c * 16 + l15) * D + h * DH + l4 * 8;
      qfB[c][0] = *(const bf16x8*)qp;
      qfB[c][1] = *(const bf16x8*)(qp + 32);
    }
  }

  f32x4 acc_o[2][4] = {};
  float m_run[2] = {-3e38f, -3e38f};
  float l_run[2] = {0.f, 0.f};

  int qb = qbA_keep;                 // current wave q base
  int qt64w = TA * 4 + (w >> 1);     // current wave diag 64-tile

  auto kv_of = [&](int j) { return (j < p1len) ? j : (j - p1len + kvoff); };
  auto stage = [&](int kv, int buf) {
    async_ld16(Kbh + (size_t)(kv * 64 + srow) * D + scol, &Ks[buf][w * 512]);
    async_ld16(Vbh + (size_t)srow * S + kv * 64 + scol, &Vs[buf][w * 512]);
  };

  stage(kv_of(0), 0);
  stage(kv_of(1), 1);

  constexpr int NST = 18;
  for (int j = 0; j < NST; ++j) {
    if (j == NST - 1)
      asm volatile("s_waitcnt vmcnt(0)\ns_barrier" ::: "memory");
    else
      asm volatile("s_waitcnt vmcnt(2)\ns_barrier" ::: "memory");
    __builtin_amdgcn_sched_barrier(0);
    if (j + 2 < NST) stage(kv_of(j + 2), (j + 2) % 3);

    if (seg == 0 && j == p1len) {
      // ---- flush FINAL output for tile p, reset for tile 7-p ----
      float lt[2], lq[2][4];
#pragma unroll
      for (int c = 0; c < 2; ++c) {
        float t = l_run[c];
        t += __shfl_xor(t, 16);
        t += __shfl_xor(t, 32);
        lt[c] = t;
#pragma unroll
        for (int r = 0; r < 4; ++r) lq[c][r] = __shfl(lt[c], l4 * 4 + r, 64);
      }
#pragma unroll
      for (int c = 0; c < 2; ++c)
#pragma unroll
        for (int db = 0; db < 4; ++db)
#pragma unroll
          for (int r = 0; r < 4; ++r) {
            const int row = c * 16 + l4 * 4 + r;
            const int col = db * 16 + l15;
            Ps[w][row * 64 + (col ^ ((row & 7) << 3))] =
                f2bf(acc_o[c][db][r] / lq[c][r]);
          }
      asm volatile("s_waitcnt lgkmcnt(0)" ::: "memory");
#pragma unroll
      for (int j4 = 0; j4 < 4; ++j4) {
        const int cid = j4 * 64 + lane;
        const int row = cid >> 3, c8 = cid & 7;
        const u16x8 vch =
            *(const u16x8*)&Ps[w][row * 64 + ((c8 ^ (row & 7)) * 8)];
        *(u16x8*)&O[(size_t)(b * S + qbA_keep + row) * D + h * DH + c8 * 8] =
            vch;
      }
      // reset state for phase B
#pragma unroll
      for (int c = 0; c < 2; ++c) {
        qf[c][0] = qfB[c][0];
        qf[c][1] = qfB[c][1];
        m_run[c] = -3e38f;
        l_run[c] = 0.f;
#pragma unroll
        for (int db = 0; db < 4; ++db) acc_o[c][db] = f32x4{0.f, 0.f, 0.f, 0.f};
      }
      qb = TB * 256 + w * 32;
      qt64w = TB * 4 + (w >> 1);
    }

    const int it = kv_of(j);
    const int buf = j % 3;
    if (it <= qt64w) {
      // ---- S^T = K Q^T (K reads shared by both q fragments) ----
      f32x4 accs[2][4] = {};
      __builtin_amdgcn_s_setprio(1);
#pragma unroll
      for (int cb = 0; cb < 4; ++cb) {
        const int row = cb * 16 + l15;
        const bf16x8 kf0 = *(const bf16x8*)&Ks[buf][row * 64 + ((l4 ^ sw) * 8)];
        const bf16x8 kf1 =
            *(const bf16x8*)&Ks[buf][row * 64 + (((l4 + 4) ^ sw) * 8)];
#pragma unroll
        for (int c = 0; c < 2; ++c) {
          accs[c][cb] = __builtin_amdgcn_mfma_f32_16x16x32_bf16(
              kf0, qf[c][0], accs[c][cb], 0, 0, 0);
          accs[c][cb] = __builtin_amdgcn_mfma_f32_16x16x32_bf16(
              kf1, qf[c][1], accs[c][cb], 0, 0, 0);
        }
      }
      __builtin_amdgcn_s_setprio(0);
      // ---- hoisted V reads (P-independent; latency hides under softmax) ----
      bf16x8 vf0[4], vf1[4];
#pragma unroll
      for (int db = 0; db < 4; ++db) {
        const int row = db * 16 + l15;
        vf0[db] = *(const bf16x8*)&Vs[buf][row * 64 + ((l4 ^ sw) * 8)];
        vf1[db] = *(const bf16x8*)&Vs[buf][row * 64 + (((l4 + 4) ^ sw) * 8)];
      }
      // ---- mask (diag) + local max ----
      float mx[2] = {-3e38f, -3e38f};
      if (it == qt64w) {
#pragma unroll
        for (int c = 0; c < 2; ++c)
#pragma unroll
          for (int cb = 0; cb < 4; ++cb)
#pragma unroll
            for (int r = 0; r < 4; ++r) {
              float s_ = accs[c][cb][r];
              if (it * 64 + cb * 16 + l4 * 4 + r > qb + c * 16 + l15)
                s_ = -3e38f;
              accs[c][cb][r] = s_;
              mx[c] = fmaxf(mx[c], s_);
            }
      } else {
#pragma unroll
        for (int c = 0; c < 2; ++c)
#pragma unroll
          for (int cb = 0; cb < 4; ++cb)
#pragma unroll
            for (int r = 0; r < 4; ++r) mx[c] = fmaxf(mx[c], accs[c][cb][r]);
      }
      // ---- defer-max: rescale only when max grew > 8 (log2 domain) ----
      if (!__all(fmaxf(mx[0] - m_run[0], mx[1] - m_run[1]) <= 8.0f)) {
#pragma unroll
        for (int c = 0; c < 2; ++c) {
          float m = mx[c];
          m = fmaxf(m, __shfl_xor(m, 16));
          m = fmaxf(m, __shfl_xor(m, 32));
          const float mn = fmaxf(m_run[c], m);
          const float corr = __builtin_amdgcn_exp2f(m_run[c] - mn);
          m_run[c] = mn;
          float cq[4];
#pragma unroll
          for (int r = 0; r < 4; ++r) cq[r] = __shfl(corr, l4 * 4 + r, 64);
#pragma unroll
          for (int db = 0; db < 4; ++db)
#pragma unroll
            for (int r = 0; r < 4; ++r) acc_o[c][db][r] *= cq[r];
          l_run[c] *= corr;
        }
      }
#pragma unroll
      for (int c = 0; c < 2; ++c) {
        float rs = 0.f;
#pragma unroll
        for (int cb = 0; cb < 4; ++cb)
#pragma unroll
          for (int r = 0; r < 4; ++r) {
            const float pv = __builtin_amdgcn_exp2f(accs[c][cb][r] - m_run[c]);
            accs[c][cb][r] = pv;
            rs += pv;
          }
        l_run[c] += rs;  // per-lane partial; reduced at flush/epilogue
      }
      // ---- pack P (both fragments) -> swizzled per-wave LDS ----
#pragma unroll
      for (int c = 0; c < 2; ++c)
#pragma unroll
        for (int cb = 0; cb < 4; ++cb) {
          bf16x4 pk = {(bf16_t)accs[c][cb][0], (bf16_t)accs[c][cb][1],
                       (bf16_t)accs[c][cb][2], (bf16_t)accs[c][cb][3]};
          const int chunk = (2 * cb + (l4 >> 1)) ^ sw;
          *(bf16x4*)&Ps[w][(c * 16 + l15) * 64 + chunk * 8 + (l4 & 1) * 4] = pk;
        }
      asm volatile("s_waitcnt lgkmcnt(0)" ::: "memory");
      bf16x8 pa[2][2];
#pragma unroll
      for (int c = 0; c < 2; ++c)
#pragma unroll
        for (int mf = 0; mf < 2; ++mf) {
          const int chunk = (mf * 4 + l4) ^ sw;
          pa[c][mf] =
              *(const bf16x8*)&Ps[w][(c * 16 + l15) * 64 + chunk * 8];
        }
      // ---- O += P V ----
      __builtin_amdgcn_s_setprio(1);
#pragma unroll
      for (int db = 0; db < 4; ++db) {
#pragma unroll
        for (int c = 0; c < 2; ++c) {
          acc_o[c][db] = __builtin_amdgcn_mfma_f32_16x16x32_bf16(
              pa[c][0], vf0[db], acc_o[c][db], 0, 0, 0);
          acc_o[c][db] = __builtin_amdgcn_mfma_f32_16x16x32_bf16(
              pa[c][1], vf1[db], acc_o[c][db], 0, 0, 0);
        }
      }
      __builtin_amdgcn_s_setprio(0);
    }
  }

  // ---- epilogue: PARTIAL write for tile 7-p (both segs) ----
  float lt[2];
#pragma unroll
  for (int c = 0; c < 2; ++c) {
    float t = l_run[c];
    t += __shfl_xor(t, 16);
    t += __shfl_xor(t, 32);
    lt[c] = t;
  }
#pragma unroll
  for (int c = 0; c < 2; ++c)
#pragma unroll
    for (int db = 0; db < 4; ++db)
#pragma unroll
      for (int r = 0; r < 4; ++r) {
        const int row = c * 16 + l4 * 4 + r;
        const int col = db * 16 + l15;
        Ps[w][row * 64 + (col ^ ((row & 7) << 3))] = f2bf(acc_o[c][db][r]);
      }
  asm volatile("s_waitcnt lgkmcnt(0)" ::: "memory");
  const size_t base =
      (size_t)seg * 32768 + (size_t)bh * 1024 + (TB * 256 + w * 32 - 1024);
#pragma unroll
  for (int j4 = 0; j4 < 4; ++j4) {
    const int cid = j4 * 64 + lane;
    const int row = cid >> 3, c8 = cid & 7;
    const u16x8 vch = *(const u16x8*)&Ps[w][row * 64 + ((c8 ^ (row & 7)) * 8)];
    *(u16x8*)&accP[(base + row) * 64 + c8 * 8] = vch;
  }
  if (l4 == 0) {
#pragma unroll
    for (int c = 0; c < 2; ++c) {
      mP[base + c * 16 + l15] = m_run[c];
      lP[base + c * 16 + l15] = lt[c];
    }
  }
}

// ---------------- combine split partials ----------------
__global__ __launch_bounds__(256) void combine_kernel(
    const u16* __restrict__ accP, const float* __restrict__ mP,
    const float* __restrict__ lP, u16* __restrict__ O) {
  const int id = blockIdx.x * 256 + threadIdx.x;  // 262144 tasks
  const int row = id >> 3;                        // 0..32767
  const int c0 = (id & 7) * 8;
  const float m0 = mP[row], m1 = mP[32768 + row];
  const float l0 = lP[row], l1 = lP[32768 + row];
  const float M = fmaxf(m0, m1);
  const float e0 = __builtin_amdgcn_exp2f(m0 - M);
  const float e1 = __builtin_amdgcn_exp2f(m1 - M);
  const float inv = 1.f / (l0 * e0 + l1 * e1);
  const bf16_t* aP = (const bf16_t*)accP;
  const bf16x8 a0 = *(const bf16x8*)&aP[(size_t)row * 64 + c0];
  const bf16x8 a1 = *(const bf16x8*)&aP[(size_t)(32768 + row) * 64 + c0];
  const int bh = row >> 10, s = 1024 + (row & 1023);
  const int b = bh >> 4, h = bh & 15;
  bf16_t* out = (bf16_t*)O + (size_t)(b * 2048 + s) * 1024 + h * 64 + c0;
  bf16x8 o;
#pragma unroll
  for (int j = 0; j < 8; ++j)
    o[j] = (bf16_t)(((float)a0[j] * e0 + (float)a1[j] * e1) * inv);
  *(bf16x8*)out = o;
}

// ---------------- launch ----------------
extern "C" void kernel_launch(void* const* d_in, const int* in_sizes, int n_in,
                              void* d_out, int out_size, void* d_ws, size_t ws_size,
                              hipStream_t stream) {
  (void)in_sizes; (void)n_in; (void)out_size;
  const float* x   = (const float*)d_in[0];
  const float* wts = (const float*)d_in[1];
  const float* Wq  = (const float*)d_in[2];
  const float* bq  = (const float*)d_in[3];
  const float* Wk  = (const float*)d_in[4];
  const float* bk  = (const float*)d_in[5];
  const float* Wv  = (const float*)d_in[6];
  const float* bv  = (const float*)d_in[7];
  const float* Wo  = (const float*)d_in[8];
  const float* bo  = (const float*)d_in[9];
  float* out = (float*)d_out;

  if (ws_size < 58724352) return;  // need ~56 MB scratch

  char* ws = (char*)d_ws;
  u16* xbf  = (u16*)(ws + 0);          // [4096,1024] bf16 (reused as accP later)
  u16* qbf  = (u16*)(ws + 8388608);
  u16* kbf  = (u16*)(ws + 16777216);
  u16* vt   = (u16*)(ws + 33554432);   // [B,H,DH,S] bf16
  u16* attn = (u16*)(ws + 41943040);   // [4096,1024] bf16
  u16* wqkv = (u16*)(ws + 50331648);   // [3072,1024] bf16 (reused as mP/lP)
  u16* wob  = (u16*)(ws + 56623104);   // Weff bf16
  float* beff = (float*)(ws + 58720256);

  // overlays (dead after gemm_qkv):
  u16* accP = xbf;                       // 2 x 32768 x 64 bf16 = 8 MB
  float* mP = (float*)(ws + 50331648);   // 2 x 32768 f32
  float* lP = mP + 65536;

  prep_kernel<<<2048, 256, 0, stream>>>(x, Wq, Wk, Wv, wts, Wo, bo,
                                        xbf, wqkv, wob, beff);
  gemm_qkv_kernel<<<dim3(12, 16), 512, 0, stream>>>(xbf, wqkv, bq, bk, bv,
                                                    qbf, kbf, vt);
  flash_kernel<<<dim3(32, 8), 512, 0, stream>>>(qbf, kbf, vt, attn,
                                                accP, mP, lP);
  combine_kernel<<<1024, 256, 0, stream>>>(accP, mP, lP, attn);
  gemm_bt_kernel<<<dim3(8, 32), 256, 0, stream>>>(
      attn, wob, beff, out, 4096, 1024, 1024);
}

// Round 15
// 104.616 us; speedup vs baseline: 1.0679x; 1.0679x over previous
//
#include <hip/hip_runtime.h>

// MultiheadAttention: B=2, S=2048, D=1024, H=16, DH=64, NF=4
// Pipeline (5 kernels) — round-10 best config + A-local out-GEMM grid:
//   1. prep: x->bf16, Wq|Wk|Wv->bf16, Weff=sum w[f]*Wout[f]->bf16, beff
//   2. qkv = x @ Wqkv^T + b   (128x128, 3-buffer counted-vmcnt pipeline;
//      q pre-scaled log2e/8; v written transposed to Vt[b,h,d,s])
//   3. flash attention v8: XCD-local grid (all 8 blocks of one bh -> one
//      XCD's L2), paired q-tiles, split-KV, swapped QK^T, defer-max
//   4. combine split partials (rows 1024..2047 per bh)
//   5. out = attn @ Weff^T + beff  (grid (32,8): row-major ids pin each
//      attn row-stripe to one XCD -> A fills once, not 8x)
typedef unsigned short u16;
typedef __bf16 bf16_t;
typedef bf16_t bf16x8 __attribute__((ext_vector_type(8)));
typedef bf16_t bf16x4 __attribute__((ext_vector_type(4)));
typedef float f32x4 __attribute__((ext_vector_type(4)));
typedef u16 u16x8 __attribute__((ext_vector_type(8)));
typedef u16 u16x4 __attribute__((ext_vector_type(4)));

#define DEV __device__ __forceinline__

DEV u16 f2bf(float f) {  // round-to-nearest-even f32 -> bf16
  unsigned u = __float_as_uint(f);
  u += 0x7FFFu + ((u >> 16) & 1u);
  return (u16)(u >> 16);
}

DEV void async_ld16(const void* g, void* lds_wave_uniform) {
  // dst is wave-uniform base; HW writes base + lane*16. Global src is per-lane.
  __builtin_amdgcn_global_load_lds(
      (const __attribute__((address_space(1))) void*)g,
      (__attribute__((address_space(3))) void*)lds_wave_uniform, 16, 0, 0);
}

// row-swizzle for 64B LDS rows (4 x 16B chunks)
DEV int KF(int r) { return (r & 3) ^ ((r >> 2) & 1); }

// ---------------- fused prep: cvt x, cvt W's, build Weff/beff ----------------
__global__ __launch_bounds__(256) void prep_kernel(
    const float* __restrict__ x, const float* __restrict__ Wq,
    const float* __restrict__ Wk, const float* __restrict__ Wv,
    const float* __restrict__ w4, const float* __restrict__ Wout,
    const float* __restrict__ bout, u16* __restrict__ xbf,
    u16* __restrict__ wqkv, u16* __restrict__ Weff, float* __restrict__ beff) {
  constexpr int NX = 1048576;            // x float4s
  constexpr int NW = 262144;             // per-W float4s
  const int stride = gridDim.x * 256;
  for (int id = blockIdx.x * 256 + threadIdx.x; id < NX + 3 * NW + NW;
       id += stride) {
    if (id < NX) {
      const float4 v = ((const float4*)x)[id];
      u16x4 o;
      o[0] = f2bf(v.x); o[1] = f2bf(v.y); o[2] = f2bf(v.z); o[3] = f2bf(v.w);
      ((u16x4*)xbf)[id] = o;
    } else if (id < NX + 3 * NW) {
      const int wi = id - NX;
      const int which = wi >> 18, j = wi & (NW - 1);
      const float* src = which == 0 ? Wq : (which == 1 ? Wk : Wv);
      const float4 v = ((const float4*)src)[j];
      u16x4 o;
      o[0] = f2bf(v.x); o[1] = f2bf(v.y); o[2] = f2bf(v.z); o[3] = f2bf(v.w);
      ((u16x4*)wqkv)[wi] = o;
    } else {
      const int i = id - NX - 3 * NW;
      const float w0 = w4[0], w1 = w4[1], w2 = w4[2], w3 = w4[3];
      const float4* W = (const float4*)Wout;
      const float4 a = W[i], b1 = W[NW + i], b2 = W[2 * NW + i],
                   b3 = W[3 * NW + i];
      u16x4 o;
      o[0] = f2bf(w0 * a.x + w1 * b1.x + w2 * b2.x + w3 * b3.x);
      o[1] = f2bf(w0 * a.y + w1 * b1.y + w2 * b2.y + w3 * b3.y);
      o[2] = f2bf(w0 * a.z + w1 * b1.z + w2 * b2.z + w3 * b3.z);
      o[3] = f2bf(w0 * a.w + w1 * b1.w + w2 * b2.w + w3 * b3.w);
      ((u16x4*)Weff)[i] = o;
      if (i < 256) {
        const float4* B4 = (const float4*)bout;
        const float4 ba = B4[i], c1 = B4[256 + i], c2 = B4[512 + i],
                     c3 = B4[768 + i];
        float4 ob;
        ob.x = w0 * ba.x + w1 * c1.x + w2 * c2.x + w3 * c3.x;
        ob.y = w0 * ba.y + w1 * c1.y + w2 * c2.y + w3 * c3.y;
        ob.z = w0 * ba.z + w1 * c1.z + w2 * c2.z + w3 * c3.z;
        ob.w = w0 * ba.w + w1 * c1.w + w2 * c2.w + w3 * c3.w;
        ((float4*)beff)[i] = ob;
      }
    }
  }
}

// ======== GEMM core: 128x128 tile, BK=32, 3-buffer counted-vmcnt pipeline ===
#define GEMM_PIPELINE_LOOP(A_, B_, m0_, n0_, K_)                               \
  int rA[2], oA[2], dstc[2];                                                   \
  _Pragma("unroll") for (int j = 0; j < 2; ++j) {                              \
    const int c = (j * 4 + w) * 64 + lane;                                     \
    rA[j] = c >> 2;                                                            \
    oA[j] = ((c & 3) ^ KF(rA[j])) * 8;                                         \
    dstc[j] = (j * 4 + w) * 512;                                               \
  }                                                                            \
  auto stage = [&](int buf, int kt) {                                          \
    _Pragma("unroll") for (int j = 0; j < 2; ++j) {                            \
      async_ld16(A_ + (m0_ + rA[j]) * K_ + kt + oA[j],                         \
                 &LDS[buf * 4096 + dstc[j]]);                                  \
      async_ld16(B_ + (n0_ + rA[j]) * K_ + kt + oA[j],                         \
                 &LDS[12288 + buf * 4096 + dstc[j]]);                          \
    }                                                                          \
  };                                                                           \
  f32x4 acc[4][4] = {};                                                        \
  stage(0, 0);                                                                 \
  stage(1, 32);                                                                \
  const int nt = K_ / 32;                                                      \
  int cur = 0, stg = 2;                                                        \
  for (int t = 0; t < nt; ++t) {                                               \
    if (t == nt - 1)                                                           \
      asm volatile("s_waitcnt vmcnt(0)\ns_barrier" ::: "memory");              \
    else                                                                       \
      asm volatile("s_waitcnt vmcnt(4)\ns_barrier" ::: "memory");              \
    __builtin_amdgcn_sched_barrier(0);                                         \
    if (t + 2 < nt) stage(stg, (t + 2) * 32);                                  \
    bf16x8 af[4], bfr[4];                                                      \
    _Pragma("unroll") for (int i = 0; i < 4; ++i) {                            \
      const int ra = wr * 64 + i * 16 + l15;                                   \
      const int rb = wc * 64 + i * 16 + l15;                                   \
      af[i] = *(const bf16x8*)&LDS[cur * 4096 + ra * 32 + ((l4 ^ KF(ra)) * 8)];\
      bfr[i] = *(const bf16x8*)&LDS[12288 + cur * 4096 + rb * 32 +             \
                                    ((l4 ^ KF(rb)) * 8)];                      \
    }                                                                          \
    __builtin_amdgcn_s_setprio(1);                                             \
    _Pragma("unroll") for (int i = 0; i < 4; ++i)                              \
        _Pragma("unroll") for (int j = 0; j < 4; ++j)                          \
            acc[i][j] = __builtin_amdgcn_mfma_f32_16x16x32_bf16(               \
                af[i], bfr[j], acc[i][j], 0, 0, 0);                            \
    __builtin_amdgcn_s_setprio(0);                                             \
    cur = cur == 2 ? 0 : cur + 1;                                              \
    stg = stg == 2 ? 0 : stg + 1;                                              \
  }

// ---------------- out GEMM: C[M,N](f32) = A @ Bw^T + bias ----------------
// grid (32, 8): blockIdx.x = row-stripe, blockIdx.y = col. Linear id =
// x + 32y ==> id%8 = x%8: all 8 col-blocks of one attn row-stripe land on
// ONE XCD -> the 256KB A-stripe fills L2 once instead of 8x.
__global__ __launch_bounds__(256) void gemm_bt_kernel(
    const u16* __restrict__ A, const u16* __restrict__ Bw,
    const float* __restrict__ bias, float* __restrict__ C, int M, int N, int K) {
  __shared__ u16 LDS[24576];
  const int tid = threadIdx.x;
  const int w = tid >> 6, lane = tid & 63;
  const int l15 = lane & 15, l4 = lane >> 4;
  const int wr = w >> 1, wc = w & 1;
  const long m0 = (long)blockIdx.x * 128, n0 = (long)blockIdx.y * 128;

  GEMM_PIPELINE_LOOP(A, Bw, m0, n0, K)

#pragma unroll
  for (int i = 0; i < 4; ++i) {
    const long row0 = m0 + wr * 64 + i * 16 + l4 * 4;
#pragma unroll
    for (int j = 0; j < 4; ++j) {
      const long col = n0 + wc * 64 + j * 16 + l15;
      const float bb = bias[col];
#pragma unroll
      for (int r = 0; r < 4; ++r)
        C[(row0 + r) * N + col] = acc[i][j][r] + bb;
    }
  }
}

// ---------------- fused QKV GEMM: [4096,1024] x [3072,1024]^T ----------------
__global__ __launch_bounds__(256) void gemm_qkv_kernel(
    const u16* __restrict__ A, const u16* __restrict__ Bw,
    const float* __restrict__ bq, const float* __restrict__ bk,
    const float* __restrict__ bv, u16* __restrict__ qo, u16* __restrict__ ko,
    u16* __restrict__ vt) {
  constexpr int K = 1024;
  __shared__ u16 LDS[24576];
  const int tid = threadIdx.x;
  const int w = tid >> 6, lane = tid & 63;
  const int l15 = lane & 15, l4 = lane >> 4;
  const int wr = w >> 1, wc = w & 1;
  const long m0 = (long)blockIdx.y * 128, n0 = (long)blockIdx.x * 128;
  const int seg = blockIdx.x >> 3;  // 0=q 1=k 2=v
  const float* bias = seg == 0 ? bq : (seg == 1 ? bk : bv);
  const float scale = seg == 0 ? 0.18033688011112042f : 1.0f;  // log2e/8

  GEMM_PIPELINE_LOOP(A, Bw, m0, n0, K)

  __syncthreads();  // all waves done with LDS staging buffers
  const long ccol0 = n0 - (long)seg * 1024;
  if (seg < 2) {
    u16* outp = seg == 0 ? qo : ko;
#pragma unroll
    for (int i = 0; i < 4; ++i) {
#pragma unroll
      for (int j = 0; j < 4; ++j) {
        const int colb = wc * 64 + j * 16 + l15;
        const float bb = bias[ccol0 + colb];
#pragma unroll
        for (int r = 0; r < 4; ++r) {
          const int row = wr * 64 + i * 16 + l4 * 4 + r;
          LDS[row * 128 + (colb ^ ((row & 15) << 3))] =
              f2bf((acc[i][j][r] + bb) * scale);
        }
      }
    }
    __syncthreads();
#pragma unroll
    for (int p = 0; p < 8; ++p) {
      const int cid = p * 256 + tid;
      const int row = cid >> 4, c = cid & 15;
      const u16x8 vch = *(const u16x8*)&LDS[row * 128 + ((c ^ (row & 15)) * 8)];
      *(u16x8*)&outp[(m0 + row) * 1024 + ccol0 + c * 8] = vch;
    }
  } else {
    const int b = (int)(m0 >> 11);
    const int s0 = (int)(m0 & 2047);
#pragma unroll
    for (int i = 0; i < 4; ++i) {
#pragma unroll
      for (int j = 0; j < 4; ++j) {
        const int colb = wc * 64 + j * 16 + l15;
        const float bb = bias[ccol0 + colb];
#pragma unroll
        for (int r = 0; r < 4; ++r) {
          const int row = wr * 64 + i * 16 + l4 * 4 + r;
          LDS[colb * 128 + (row ^ ((colb & 15) << 3))] = f2bf(acc[i][j][r] + bb);
        }
      }
    }
    __syncthreads();
#pragma unroll
    for (int p = 0; p < 8; ++p) {
      const int cid = p * 256 + tid;
      const int c = cid >> 4, r0 = (cid & 15) * 8;
      const u16x8 vch = *(const u16x8*)&LDS[c * 128 + (r0 ^ ((c & 15) << 3))];
      const int gcol = (int)ccol0 + c;
      const int h = gcol >> 6, d = gcol & 63;
      *(u16x8*)&vt[(size_t)((b * 16 + h) * 64 + d) * 2048 + s0 + r0] = vch;
    }
  }
}

// ---------------- causal flash attention v8 ----------------
// grid (32, 8): blockIdx.x = bh, blockIdx.y = xb. Linear block id =
// bh + 32*xb -> XCD = bh % 8: ALL 8 blocks of one bh land on the same XCD,
// so its K/V (512 KB) stays L2-resident (4 bh x 512 KB = 2 MB / 4 MB L2).
// xb: p = xb>>1, seg = xb&1. Macro q-tiles (256 rows) pair (p, 7-p):
//   seg0: tile p, kv 0..4p+3 (final) then tile 7-p, kv 0..13-4p (partial 0)
//   seg1: tile 7-p, kv 14-4p..31-4p (partial 1)
// Each block exactly 18 KV steps. Triple-buffered K/V, vmcnt(2) barriers.
// V-reads hoisted above softmax (P-independent, latency hides under exp2).
__global__ __launch_bounds__(512) void flash_kernel(
    const u16* __restrict__ Q, const u16* __restrict__ Kg,
    const u16* __restrict__ Vt, u16* __restrict__ O,
    u16* __restrict__ accP, float* __restrict__ mP, float* __restrict__ lP) {
  constexpr int S = 2048, D = 1024, DH = 64;
  __shared__ u16 Ks[3][4096];  // [key][feat], XOR-swizzled 16B chunks
  __shared__ u16 Vs[3][4096];  // [d][key]
  __shared__ u16 Ps[8][2048];  // per-wave 32q x 64key
  const int tid = threadIdx.x;
  const int w = tid >> 6, lane = tid & 63;
  const int l15 = lane & 15, l4 = lane >> 4;
  const int bh = blockIdx.x, b = bh >> 4, h = bh & 15;
  const int xb = blockIdx.y;
  const int p = xb >> 1, seg = xb & 1;
  const int p1len = seg ? 0 : 4 * p + 4;
  const int kvoff = seg ? (14 - 4 * p) : 0;
  const int TA = seg ? (7 - p) : p;
  const int TB = 7 - p;
  const int qbA_keep = TA * 256 + w * 32;  // for the mid-loop final flush

  const u16* Kbh = Kg + (size_t)b * S * D + h * DH;
  const u16* Vbh = Vt + (size_t)bh * DH * S;

  const int srow = tid >> 3;
  const int scol = ((tid & 7) ^ (srow & 7)) * 8;
  const int sw = l15 & 7;

  // Q fragments: working set qf (phase A) and preloaded qfB (phase B, seg0)
  bf16x8 qf[2][2], qfB[2][2];
#pragma unroll
  for (int c = 0; c < 2; ++c) {
    const u16* qp =
        Q + (size_t)(b * S + qbA_keep + c * 16 + l15) * D + h * DH + l4 * 8;
    qf[c][0] = *(const bf16x8*)qp;
    qf[c][1] = *(const bf16x8*)(qp + 32);
    qfB[c][0] = qf[c][0];
    qfB[c][1] = qf[c][1];
  }
  if (!seg) {
    const int qbB = TB * 256 + w * 32;
#pragma unroll
    for (int c = 0; c < 2; ++c) {
      const u16* qp =
          Q + (size_t)(b * S + qbB + c * 16 + l15) * D + h * DH + l4 * 8;
      qfB[c][0] = *(const bf16x8*)qp;
      qfB[c][1] = *(const bf16x8*)(qp + 32);
    }
  }

  f32x4 acc_o[2][4] = {};
  float m_run[2] = {-3e38f, -3e38f};
  float l_run[2] = {0.f, 0.f};

  int qb = qbA_keep;                 // current wave q base
  int qt64w = TA * 4 + (w >> 1);     // current wave diag 64-tile

  auto kv_of = [&](int j) { return (j < p1len) ? j : (j - p1len + kvoff); };
  auto stage = [&](int kv, int buf) {
    async_ld16(Kbh + (size_t)(kv * 64 + srow) * D + scol, &Ks[buf][w * 512]);
    async_ld16(Vbh + (size_t)srow * S + kv * 64 + scol, &Vs[buf][w * 512]);
  };

  stage(kv_of(0), 0);
  stage(kv_of(1), 1);

  constexpr int NST = 18;
  for (int j = 0; j < NST; ++j) {
    if (j == NST - 1)
      asm volatile("s_waitcnt vmcnt(0)\ns_barrier" ::: "memory");
    else
      asm volatile("s_waitcnt vmcnt(2)\ns_barrier" ::: "memory");
    __builtin_amdgcn_sched_barrier(0);
    if (j + 2 < NST) stage(kv_of(j + 2), (j + 2) % 3);

    if (seg == 0 && j == p1len) {
      // ---- flush FINAL output for tile p, reset for tile 7-p ----
      float lt[2], lq[2][4];
#pragma unroll
      for (int c = 0; c < 2; ++c) {
        float t = l_run[c];
        t += __shfl_xor(t, 16);
        t += __shfl_xor(t, 32);
        lt[c] = t;
#pragma unroll
        for (int r = 0; r < 4; ++r) lq[c][r] = __shfl(lt[c], l4 * 4 + r, 64);
      }
#pragma unroll
      for (int c = 0; c < 2; ++c)
#pragma unroll
        for (int db = 0; db < 4; ++db)
#pragma unroll
          for (int r = 0; r < 4; ++r) {
            const int row = c * 16 + l4 * 4 + r;
            const int col = db * 16 + l15;
            Ps[w][row * 64 + (col ^ ((row & 7) << 3))] =
                f2bf(acc_o[c][db][r] / lq[c][r]);
          }
      asm volatile("s_waitcnt lgkmcnt(0)" ::: "memory");
#pragma unroll
      for (int j4 = 0; j4 < 4; ++j4) {
        const int cid = j4 * 64 + lane;
        const int row = cid >> 3, c8 = cid & 7;
        const u16x8 vch =
            *(const u16x8*)&Ps[w][row * 64 + ((c8 ^ (row & 7)) * 8)];
        *(u16x8*)&O[(size_t)(b * S + qbA_keep + row) * D + h * DH + c8 * 8] =
            vch;
      }
      // reset state for phase B
#pragma unroll
      for (int c = 0; c < 2; ++c) {
        qf[c][0] = qfB[c][0];
        qf[c][1] = qfB[c][1];
        m_run[c] = -3e38f;
        l_run[c] = 0.f;
#pragma unroll
        for (int db = 0; db < 4; ++db) acc_o[c][db] = f32x4{0.f, 0.f, 0.f, 0.f};
      }
      qb = TB * 256 + w * 32;
      qt64w = TB * 4 + (w >> 1);
    }

    const int it = kv_of(j);
    const int buf = j % 3;
    if (it <= qt64w) {
      // ---- S^T = K Q^T (K reads shared by both q fragments) ----
      f32x4 accs[2][4] = {};
      __builtin_amdgcn_s_setprio(1);
#pragma unroll
      for (int cb = 0; cb < 4; ++cb) {
        const int row = cb * 16 + l15;
        const bf16x8 kf0 = *(const bf16x8*)&Ks[buf][row * 64 + ((l4 ^ sw) * 8)];
        const bf16x8 kf1 =
            *(const bf16x8*)&Ks[buf][row * 64 + (((l4 + 4) ^ sw) * 8)];
#pragma unroll
        for (int c = 0; c < 2; ++c) {
          accs[c][cb] = __builtin_amdgcn_mfma_f32_16x16x32_bf16(
              kf0, qf[c][0], accs[c][cb], 0, 0, 0);
          accs[c][cb] = __builtin_amdgcn_mfma_f32_16x16x32_bf16(
              kf1, qf[c][1], accs[c][cb], 0, 0, 0);
        }
      }
      __builtin_amdgcn_s_setprio(0);
      // ---- hoisted V reads (P-independent; latency hides under softmax) ----
      bf16x8 vf0[4], vf1[4];
#pragma unroll
      for (int db = 0; db < 4; ++db) {
        const int row = db * 16 + l15;
        vf0[db] = *(const bf16x8*)&Vs[buf][row * 64 + ((l4 ^ sw) * 8)];
        vf1[db] = *(const bf16x8*)&Vs[buf][row * 64 + (((l4 + 4) ^ sw) * 8)];
      }
      // ---- mask (diag) + local max ----
      float mx[2] = {-3e38f, -3e38f};
      if (it == qt64w) {
#pragma unroll
        for (int c = 0; c < 2; ++c)
#pragma unroll
          for (int cb = 0; cb < 4; ++cb)
#pragma unroll
            for (int r = 0; r < 4; ++r) {
              float s_ = accs[c][cb][r];
              if (it * 64 + cb * 16 + l4 * 4 + r > qb + c * 16 + l15)
                s_ = -3e38f;
              accs[c][cb][r] = s_;
              mx[c] = fmaxf(mx[c], s_);
            }
      } else {
#pragma unroll
        for (int c = 0; c < 2; ++c)
#pragma unroll
          for (int cb = 0; cb < 4; ++cb)
#pragma unroll
            for (int r = 0; r < 4; ++r) mx[c] = fmaxf(mx[c], accs[c][cb][r]);
      }
      // ---- defer-max: rescale only when max grew > 8 (log2 domain) ----
      if (!__all(fmaxf(mx[0] - m_run[0], mx[1] - m_run[1]) <= 8.0f)) {
#pragma unroll
        for (int c = 0; c < 2; ++c) {
          float m = mx[c];
          m = fmaxf(m, __shfl_xor(m, 16));
          m = fmaxf(m, __shfl_xor(m, 32));
          const float mn = fmaxf(m_run[c], m);
          const float corr = __builtin_amdgcn_exp2f(m_run[c] - mn);
          m_run[c] = mn;
          float cq[4];
#pragma unroll
          for (int r = 0; r < 4; ++r) cq[r] = __shfl(corr, l4 * 4 + r, 64);
#pragma unroll
          for (int db = 0; db < 4; ++db)
#pragma unroll
            for (int r = 0; r < 4; ++r) acc_o[c][db][r] *= cq[r];
          l_run[c] *= corr;
        }
      }
#pragma unroll
      for (int c = 0; c < 2; ++c) {
        float rs = 0.f;
#pragma unroll
        for (int cb = 0; cb < 4; ++cb)
#pragma unroll
          for (int r = 0; r < 4; ++r) {
            const float pv = __builtin_amdgcn_exp2f(accs[c][cb][r] - m_run[c]);
            accs[c][cb][r] = pv;
            rs += pv;
          }
        l_run[c] += rs;  // per-lane partial; reduced at flush/epilogue
      }
      // ---- pack P (both fragments) -> swizzled per-wave LDS ----
#pragma unroll
      for (int c = 0; c < 2; ++c)
#pragma unroll
        for (int cb = 0; cb < 4; ++cb) {
          bf16x4 pk = {(bf16_t)accs[c][cb][0], (bf16_t)accs[c][cb][1],
                       (bf16_t)accs[c][cb][2], (bf16_t)accs[c][cb][3]};
          const int chunk = (2 * cb + (l4 >> 1)) ^ sw;
          *(bf16x4*)&Ps[w][(c * 16 + l15) * 64 + chunk * 8 + (l4 & 1) * 4] = pk;
        }
      asm volatile("s_waitcnt lgkmcnt(0)" ::: "memory");
      bf16x8 pa[2][2];
#pragma unroll
      for (int c = 0; c < 2; ++c)
#pragma unroll
        for (int mf = 0; mf < 2; ++mf) {
          const int chunk = (mf * 4 + l4) ^ sw;
          pa[c][mf] =
              *(const bf16x8*)&Ps[w][(c * 16 + l15) * 64 + chunk * 8];
        }
      // ---- O += P V ----
      __builtin_amdgcn_s_setprio(1);
#pragma unroll
      for (int db = 0; db < 4; ++db) {
#pragma unroll
        for (int c = 0; c < 2; ++c) {
          acc_o[c][db] = __builtin_amdgcn_mfma_f32_16x16x32_bf16(
              pa[c][0], vf0[db], acc_o[c][db], 0, 0, 0);
          acc_o[c][db] = __builtin_amdgcn_mfma_f32_16x16x32_bf16(
              pa[c][1], vf1[db], acc_o[c][db], 0, 0, 0);
        }
      }
      __builtin_amdgcn_s_setprio(0);
    }
  }

  // ---- epilogue: PARTIAL write for tile 7-p (both segs) ----
  float lt[2];
#pragma unroll
  for (int c = 0; c < 2; ++c) {
    float t = l_run[c];
    t += __shfl_xor(t, 16);
    t += __shfl_xor(t, 32);
    lt[c] = t;
  }
#pragma unroll
  for (int c = 0; c < 2; ++c)
#pragma unroll
    for (int db = 0; db < 4; ++db)
#pragma unroll
      for (int r = 0; r < 4; ++r) {
        const int row = c * 16 + l4 * 4 + r;
        const int col = db * 16 + l15;
        Ps[w][row * 64 + (col ^ ((row & 7) << 3))] = f2bf(acc_o[c][db][r]);
      }
  asm volatile("s_waitcnt lgkmcnt(0)" ::: "memory");
  const size_t base =
      (size_t)seg * 32768 + (size_t)bh * 1024 + (TB * 256 + w * 32 - 1024);
#pragma unroll
  for (int j4 = 0; j4 < 4; ++j4) {
    const int cid = j4 * 64 + lane;
    const int row = cid >> 3, c8 = cid & 7;
    const u16x8 vch = *(const u16x8*)&Ps[w][row * 64 + ((c8 ^ (row & 7)) * 8)];
    *(u16x8*)&accP[(base + row) * 64 + c8 * 8] = vch;
  }
  if (l4 == 0) {
#pragma unroll
    for (int c = 0; c < 2; ++c) {
      mP[base + c * 16 + l15] = m_run[c];
      lP[base + c * 16 + l15] = lt[c];
    }
  }
}

// ---------------- combine split partials ----------------
__global__ __launch_bounds__(256) void combine_kernel(
    const u16* __restrict__ accP, const float* __restrict__ mP,
    const float* __restrict__ lP, u16* __restrict__ O) {
  const int id = blockIdx.x * 256 + threadIdx.x;  // 262144 tasks
  const int row = id >> 3;                        // 0..32767
  const int c0 = (id & 7) * 8;
  const float m0 = mP[row], m1 = mP[32768 + row];
  const float l0 = lP[row], l1 = lP[32768 + row];
  const float M = fmaxf(m0, m1);
  const float e0 = __builtin_amdgcn_exp2f(m0 - M);
  const float e1 = __builtin_amdgcn_exp2f(m1 - M);
  const float inv = 1.f / (l0 * e0 + l1 * e1);
  const bf16_t* aP = (const bf16_t*)accP;
  const bf16x8 a0 = *(const bf16x8*)&aP[(size_t)row * 64 + c0];
  const bf16x8 a1 = *(const bf16x8*)&aP[(size_t)(32768 + row) * 64 + c0];
  const int bh = row >> 10, s = 1024 + (row & 1023);
  const int b = bh >> 4, h = bh & 15;
  bf16_t* out = (bf16_t*)O + (size_t)(b * 2048 + s) * 1024 + h * 64 + c0;
  bf16x8 o;
#pragma unroll
  for (int j = 0; j < 8; ++j)
    o[j] = (bf16_t)(((float)a0[j] * e0 + (float)a1[j] * e1) * inv);
  *(bf16x8*)out = o;
}

// ---------------- launch ----------------
extern "C" void kernel_launch(void* const* d_in, const int* in_sizes, int n_in,
                              void* d_out, int out_size, void* d_ws, size_t ws_size,
                              hipStream_t stream) {
  (void)in_sizes; (void)n_in; (void)out_size;
  const float* x   = (const float*)d_in[0];
  const float* wts = (const float*)d_in[1];
  const float* Wq  = (const float*)d_in[2];
  const float* bq  = (const float*)d_in[3];
  const float* Wk  = (const float*)d_in[4];
  const float* bk  = (const float*)d_in[5];
  const float* Wv  = (const float*)d_in[6];
  const float* bv  = (const float*)d_in[7];
  const float* Wo  = (const float*)d_in[8];
  const float* bo  = (const float*)d_in[9];
  float* out = (float*)d_out;

  if (ws_size < 58724352) return;  // need ~56 MB scratch

  char* ws = (char*)d_ws;
  u16* xbf  = (u16*)(ws + 0);          // [4096,1024] bf16 (reused as accP later)
  u16* qbf  = (u16*)(ws + 8388608);
  u16* kbf  = (u16*)(ws + 16777216);
  u16* vt   = (u16*)(ws + 33554432);   // [B,H,DH,S] bf16
  u16* attn = (u16*)(ws + 41943040);   // [4096,1024] bf16
  u16* wqkv = (u16*)(ws + 50331648);   // [3072,1024] bf16 (reused as mP/lP)
  u16* wob  = (u16*)(ws + 56623104);   // Weff bf16
  float* beff = (float*)(ws + 58720256);

  // overlays (dead after gemm_qkv):
  u16* accP = xbf;                       // 2 x 32768 x 64 bf16 = 8 MB
  float* mP = (float*)(ws + 50331648);   // 2 x 32768 f32
  float* lP = mP + 65536;

  prep_kernel<<<2048, 256, 0, stream>>>(x, Wq, Wk, Wv, wts, Wo, bo,
                                        xbf, wqkv, wob, beff);
  gemm_qkv_kernel<<<dim3(24, 32), 256, 0, stream>>>(xbf, wqkv, bq, bk, bv,
                                                    qbf, kbf, vt);
  flash_kernel<<<dim3(32, 8), 512, 0, stream>>>(qbf, kbf, vt, attn,
                                                accP, mP, lP);
  combine_kernel<<<1024, 256, 0, stream>>>(accP, mP, lP, attn);
  gemm_bt_kernel<<<dim3(32, 8), 256, 0, stream>>>(
      attn, wob, beff, out, 4096, 1024, 1024);
}

// Round 16
// 103.166 us; speedup vs baseline: 1.0829x; 1.0141x over previous
//
#include <hip/hip_runtime.h>

// MultiheadAttention: B=2, S=2048, D=1024, H=16, DH=64, NF=4
// Pipeline (5 kernels):
//   1. prep: x->bf16, Wq|Wk|Wv->bf16, Weff=sum w[f]*Wout[f]->bf16, beff
//   2. qkv v4: 256x256 tile, 8 waves, BK=64, 2-slot LDS; ONE vmcnt(0)+barrier
//      per 64 MFMA; staging always targets the idle slot (race-free);
//      q pre-scaled log2e/8; v written transposed to Vt[b,h,d,s]
//   3. flash attention v8: XCD-local grid, paired q-tiles, split-KV,
//      swapped QK^T, defer-max
//   4. combine split partials (rows 1024..2047 per bh)
//   5. out = attn @ Weff^T + beff  (128x128, 3-buffer pipeline, A-local grid)
typedef unsigned short u16;
typedef __bf16 bf16_t;
typedef bf16_t bf16x8 __attribute__((ext_vector_type(8)));
typedef bf16_t bf16x4 __attribute__((ext_vector_type(4)));
typedef float f32x4 __attribute__((ext_vector_type(4)));
typedef u16 u16x8 __attribute__((ext_vector_type(8)));
typedef u16 u16x4 __attribute__((ext_vector_type(4)));

#define DEV __device__ __forceinline__

DEV u16 f2bf(float f) {  // round-to-nearest-even f32 -> bf16
  unsigned u = __float_as_uint(f);
  u += 0x7FFFu + ((u >> 16) & 1u);
  return (u16)(u >> 16);
}

DEV void async_ld16(const void* g, void* lds_wave_uniform) {
  // dst is wave-uniform base; HW writes base + lane*16. Global src is per-lane.
  __builtin_amdgcn_global_load_lds(
      (const __attribute__((address_space(1))) void*)g,
      (__attribute__((address_space(3))) void*)lds_wave_uniform, 16, 0, 0);
}

// row-swizzle for 64B LDS rows (4 x 16B chunks)
DEV int KF(int r) { return (r & 3) ^ ((r >> 2) & 1); }

// ---------------- fused prep: cvt x, cvt W's, build Weff/beff ----------------
__global__ __launch_bounds__(256) void prep_kernel(
    const float* __restrict__ x, const float* __restrict__ Wq,
    const float* __restrict__ Wk, const float* __restrict__ Wv,
    const float* __restrict__ w4, const float* __restrict__ Wout,
    const float* __restrict__ bout, u16* __restrict__ xbf,
    u16* __restrict__ wqkv, u16* __restrict__ Weff, float* __restrict__ beff) {
  constexpr int NX = 1048576;            // x float4s
  constexpr int NW = 262144;             // per-W float4s
  const int stride = gridDim.x * 256;
  for (int id = blockIdx.x * 256 + threadIdx.x; id < NX + 3 * NW + NW;
       id += stride) {
    if (id < NX) {
      const float4 v = ((const float4*)x)[id];
      u16x4 o;
      o[0] = f2bf(v.x); o[1] = f2bf(v.y); o[2] = f2bf(v.z); o[3] = f2bf(v.w);
      ((u16x4*)xbf)[id] = o;
    } else if (id < NX + 3 * NW) {
      const int wi = id - NX;
      const int which = wi >> 18, j = wi & (NW - 1);
      const float* src = which == 0 ? Wq : (which == 1 ? Wk : Wv);
      const float4 v = ((const float4*)src)[j];
      u16x4 o;
      o[0] = f2bf(v.x); o[1] = f2bf(v.y); o[2] = f2bf(v.z); o[3] = f2bf(v.w);
      ((u16x4*)wqkv)[wi] = o;
    } else {
      const int i = id - NX - 3 * NW;
      const float w0 = w4[0], w1 = w4[1], w2 = w4[2], w3 = w4[3];
      const float4* W = (const float4*)Wout;
      const float4 a = W[i], b1 = W[NW + i], b2 = W[2 * NW + i],
                   b3 = W[3 * NW + i];
      u16x4 o;
      o[0] = f2bf(w0 * a.x + w1 * b1.x + w2 * b2.x + w3 * b3.x);
      o[1] = f2bf(w0 * a.y + w1 * b1.y + w2 * b2.y + w3 * b3.y);
      o[2] = f2bf(w0 * a.z + w1 * b1.z + w2 * b2.z + w3 * b3.z);
      o[3] = f2bf(w0 * a.w + w1 * b1.w + w2 * b2.w + w3 * b3.w);
      ((u16x4*)Weff)[i] = o;
      if (i < 256) {
        const float4* B4 = (const float4*)bout;
        const float4 ba = B4[i], c1 = B4[256 + i], c2 = B4[512 + i],
                     c3 = B4[768 + i];
        float4 ob;
        ob.x = w0 * ba.x + w1 * c1.x + w2 * c2.x + w3 * c3.x;
        ob.y = w0 * ba.y + w1 * c1.y + w2 * c2.y + w3 * c3.y;
        ob.z = w0 * ba.z + w1 * c1.z + w2 * c2.z + w3 * c3.z;
        ob.w = w0 * ba.w + w1 * c1.w + w2 * c2.w + w3 * c3.w;
        ((float4*)beff)[i] = ob;
      }
    }
  }
}

// ======== GEMM core: 128x128 tile, BK=32, 3-buffer counted-vmcnt pipeline ===
#define GEMM_PIPELINE_LOOP(A_, B_, m0_, n0_, K_)                               \
  int rA[2], oA[2], dstc[2];                                                   \
  _Pragma("unroll") for (int j = 0; j < 2; ++j) {                              \
    const int c = (j * 4 + w) * 64 + lane;                                     \
    rA[j] = c >> 2;                                                            \
    oA[j] = ((c & 3) ^ KF(rA[j])) * 8;                                         \
    dstc[j] = (j * 4 + w) * 512;                                               \
  }                                                                            \
  auto stage = [&](int buf, int kt) {                                          \
    _Pragma("unroll") for (int j = 0; j < 2; ++j) {                            \
      async_ld16(A_ + (m0_ + rA[j]) * K_ + kt + oA[j],                         \
                 &LDS[buf * 4096 + dstc[j]]);                                  \
      async_ld16(B_ + (n0_ + rA[j]) * K_ + kt + oA[j],                         \
                 &LDS[12288 + buf * 4096 + dstc[j]]);                          \
    }                                                                          \
  };                                                                           \
  f32x4 acc[4][4] = {};                                                        \
  stage(0, 0);                                                                 \
  stage(1, 32);                                                                \
  const int nt = K_ / 32;                                                      \
  int cur = 0, stg = 2;                                                        \
  for (int t = 0; t < nt; ++t) {                                               \
    if (t == nt - 1)                                                           \
      asm volatile("s_waitcnt vmcnt(0)\ns_barrier" ::: "memory");              \
    else                                                                       \
      asm volatile("s_waitcnt vmcnt(4)\ns_barrier" ::: "memory");              \
    __builtin_amdgcn_sched_barrier(0);                                         \
    if (t + 2 < nt) stage(stg, (t + 2) * 32);                                  \
    bf16x8 af[4], bfr[4];                                                      \
    _Pragma("unroll") for (int i = 0; i < 4; ++i) {                            \
      const int ra = wr * 64 + i * 16 + l15;                                   \
      const int rb = wc * 64 + i * 16 + l15;                                   \
      af[i] = *(const bf16x8*)&LDS[cur * 4096 + ra * 32 + ((l4 ^ KF(ra)) * 8)];\
      bfr[i] = *(const bf16x8*)&LDS[12288 + cur * 4096 + rb * 32 +             \
                                    ((l4 ^ KF(rb)) * 8)];                      \
    }                                                                          \
    __builtin_amdgcn_s_setprio(1);                                             \
    _Pragma("unroll") for (int i = 0; i < 4; ++i)                              \
        _Pragma("unroll") for (int j = 0; j < 4; ++j)                          \
            acc[i][j] = __builtin_amdgcn_mfma_f32_16x16x32_bf16(               \
                af[i], bfr[j], acc[i][j], 0, 0, 0);                            \
    __builtin_amdgcn_s_setprio(0);                                             \
    cur = cur == 2 ? 0 : cur + 1;                                              \
    stg = stg == 2 ? 0 : stg + 1;                                              \
  }

// ---------------- out GEMM: C[M,N](f32) = A @ Bw^T + bias ----------------
// grid (32, 8): row-major ids pin each attn row-stripe to one XCD.
__global__ __launch_bounds__(256) void gemm_bt_kernel(
    const u16* __restrict__ A, const u16* __restrict__ Bw,
    const float* __restrict__ bias, float* __restrict__ C, int M, int N, int K) {
  __shared__ u16 LDS[24576];
  const int tid = threadIdx.x;
  const int w = tid >> 6, lane = tid & 63;
  const int l15 = lane & 15, l4 = lane >> 4;
  const int wr = w >> 1, wc = w & 1;
  const long m0 = (long)blockIdx.x * 128, n0 = (long)blockIdx.y * 128;

  GEMM_PIPELINE_LOOP(A, Bw, m0, n0, K)

#pragma unroll
  for (int i = 0; i < 4; ++i) {
    const long row0 = m0 + wr * 64 + i * 16 + l4 * 4;
#pragma unroll
    for (int j = 0; j < 4; ++j) {
      const long col = n0 + wc * 64 + j * 16 + l15;
      const float bb = bias[col];
#pragma unroll
      for (int r = 0; r < 4; ++r)
        C[(row0 + r) * N + col] = acc[i][j][r] + bb;
    }
  }
}

// -------- fused QKV GEMM v4: 256x256, 8 waves, BK=64, 2-slot, 1 barrier/64MFMA
// grid (12,16): blockIdx.x = 256-col tile (0-3 q, 4-7 k, 8-11 v).
// LDS 128KB: A slots 2 x 16384 u16 @0; B slots @32768. Rows are 128B =
// 8 x 16B chunks, chunk c of row r stored at c ^ (r&7) (2-way conflicts).
// Half-iter t (t = 0..15): head {vmcnt(0); s_barrier} retires tile t's 8
// loads; compute tile t from slot t&1 (64 MFMA/wave), staging tile t+1 into
// slot (t+1)&1 at 4 issue points spread between MFMA quads. Slot being
// staged is idle (its last reader finished half-iter t-1, proven by the
// head barrier) -> race-free with ONE barrier per 64 MFMA.
__global__ __launch_bounds__(512) void gemm_qkv_kernel(
    const u16* __restrict__ A, const u16* __restrict__ Bw,
    const float* __restrict__ bq, const float* __restrict__ bk,
    const float* __restrict__ bv, u16* __restrict__ qo, u16* __restrict__ ko,
    u16* __restrict__ vt) {
  constexpr int K = 1024;
  __shared__ u16 LDS[65536];  // 128 KB
  const int tid = threadIdx.x;
  const int w = tid >> 6, lane = tid & 63;
  const int l15 = lane & 15, l4 = lane >> 4;
  const int wr = w >> 2, wc = w & 3;
  const long m0 = (long)blockIdx.y * 256, n0 = (long)blockIdx.x * 256;
  const int seg = blockIdx.x >> 2;  // 0=q 1=k 2=v
  const float* bias = seg == 0 ? bq : (seg == 1 ? bk : bv);
  const float scale = seg == 0 ? 0.18033688011112042f : 1.0f;  // log2e/8

  // staging geometry: half-tile = 128 rows x 64 k = 1024 chunks of 16B;
  // 512 threads x 2 loads. thread covers chunk c = j*512 + tid.
  const int sr0 = tid >> 3;                              // rows 0..63 (j=0)
  const int soff = ((tid & 7) ^ ((tid >> 3) & 7)) * 8;   // swizzled src col
  // stage half-tile h (0:A rows0-127,1:A rows128-255,2:B r0-127,3:B r128-255)
  auto stage_half = [&](int k, int h) {
    const int slot = k & 1;
    const int base =
        (h < 2 ? 0 : 32768) + slot * 16384 + (h & 1) * 8192;  // u16
    const long row0 = (h < 2 ? m0 : n0) + (h & 1) * 128;
    const u16* M = (h < 2) ? A : Bw;
    const int kt = k * 64;
    async_ld16(M + (row0 + sr0) * K + kt + soff, &LDS[base + w * 512]);
    async_ld16(M + (row0 + 64 + sr0) * K + kt + soff,
               &LDS[base + 4096 + w * 512]);
  };

  f32x4 acc[8][4] = {};
  // prologue: tile 0 fully staged (8 loads)
#pragma unroll
  for (int h = 0; h < 4; ++h) stage_half(0, h);

  for (int t = 0; t < 16; ++t) {
    asm volatile("s_waitcnt vmcnt(0)\ns_barrier" ::: "memory");
    const int slot = t & 1;
    const int abase = slot * 16384;
    const int bbase = 32768 + slot * 16384;
    const bool st = (t + 1) < 16;
    // B fragments for the whole K-tile (4 cols x 2 kslices)
    bf16x8 bfr[4][2];
#pragma unroll
    for (int j = 0; j < 4; ++j) {
      const int rb = wc * 64 + j * 16 + l15;
#pragma unroll
      for (int ks = 0; ks < 2; ++ks)
        bfr[j][ks] = *(const bf16x8*)&LDS[bbase + rb * 64 +
                                          (((ks * 4 + l4) ^ (rb & 7)) * 8)];
    }
#pragma unroll
    for (int ph = 0; ph < 4; ++ph) {
      if (st) stage_half(t + 1, ph);  // idle slot; 4 spread issue points
      const int ra0 = wr * 128 + (2 * ph) * 16 + l15;
      const int ra1 = wr * 128 + (2 * ph + 1) * 16 + l15;
      bf16x8 af0[2], af1[2];
#pragma unroll
      for (int ks = 0; ks < 2; ++ks) {
        af0[ks] = *(const bf16x8*)&LDS[abase + ra0 * 64 +
                                       (((ks * 4 + l4) ^ (ra0 & 7)) * 8)];
        af1[ks] = *(const bf16x8*)&LDS[abase + ra1 * 64 +
                                       (((ks * 4 + l4) ^ (ra1 & 7)) * 8)];
      }
      __builtin_amdgcn_s_setprio(1);
#pragma unroll
      for (int j = 0; j < 4; ++j) {
        acc[2 * ph][j] = __builtin_amdgcn_mfma_f32_16x16x32_bf16(
            af0[0], bfr[j][0], acc[2 * ph][j], 0, 0, 0);
        acc[2 * ph][j] = __builtin_amdgcn_mfma_f32_16x16x32_bf16(
            af0[1], bfr[j][1], acc[2 * ph][j], 0, 0, 0);
        acc[2 * ph + 1][j] = __builtin_amdgcn_mfma_f32_16x16x32_bf16(
            af1[0], bfr[j][0], acc[2 * ph + 1][j], 0, 0, 0);
        acc[2 * ph + 1][j] = __builtin_amdgcn_mfma_f32_16x16x32_bf16(
            af1[1], bfr[j][1], acc[2 * ph + 1][j], 0, 0, 0);
      }
      __builtin_amdgcn_s_setprio(0);
    }
  }

  __syncthreads();  // staging LDS now free for epilogue tiles
  const long ccol0 = n0 - (long)seg * 1024;
  if (seg < 2) {
    // ---- q/k epilogue: two 256x128 halves, swizzled LDS -> u16x8 stores ----
    u16* outp = seg == 0 ? qo : ko;
#pragma unroll
    for (int h = 0; h < 2; ++h) {
      if ((wc >> 1) == h) {
#pragma unroll
        for (int i = 0; i < 8; ++i)
#pragma unroll
          for (int j = 0; j < 4; ++j) {
            const int colb = (wc & 1) * 64 + j * 16 + l15;  // 0..127
            const float bb = bias[ccol0 + h * 128 + colb];
#pragma unroll
            for (int r = 0; r < 4; ++r) {
              const int row = wr * 128 + i * 16 + l4 * 4 + r;
              LDS[row * 128 + (colb ^ ((row & 15) << 3))] =
                  f2bf((acc[i][j][r] + bb) * scale);
            }
          }
      }
      __syncthreads();
#pragma unroll
      for (int p = 0; p < 8; ++p) {
        const int cid = p * 512 + tid;
        const int row = cid >> 4, c = cid & 15;
        const u16x8 vch =
            *(const u16x8*)&LDS[row * 128 + ((c ^ (row & 15)) * 8)];
        *(u16x8*)&outp[(m0 + row) * 1024 + ccol0 + h * 128 + c * 8] = vch;
      }
      __syncthreads();
    }
  } else {
    // ---- v epilogue: two transposed 128x256 halves -> Vt[b,h,d,s] ----
    const int b = (int)(m0 >> 11);
    const int s0 = (int)(m0 & 2047);
#pragma unroll
    for (int h = 0; h < 2; ++h) {
      if ((wc >> 1) == h) {
#pragma unroll
        for (int i = 0; i < 8; ++i)
#pragma unroll
          for (int j = 0; j < 4; ++j) {
            const int colb = (wc & 1) * 64 + j * 16 + l15;  // 0..127
            const float bb = bias[ccol0 + h * 128 + colb];
#pragma unroll
            for (int r = 0; r < 4; ++r) {
              const int row = wr * 128 + i * 16 + l4 * 4 + r;  // 0..255
              LDS[colb * 256 + (row ^ ((colb & 15) << 3))] =
                  f2bf(acc[i][j][r] + bb);
            }
          }
      }
      __syncthreads();
#pragma unroll
      for (int p = 0; p < 8; ++p) {
        const int cid = p * 512 + tid;
        const int c = cid >> 5, r0 = (cid & 31) * 8;  // c 0..127, r0 0..248
        const u16x8 vch = *(const u16x8*)&LDS[c * 256 + (r0 ^ ((c & 15) << 3))];
        const int gcol = (int)ccol0 + h * 128 + c;  // 0..1023 within v
        const int hh = gcol >> 6, d = gcol & 63;
        *(u16x8*)&vt[(size_t)((b * 16 + hh) * 64 + d) * 2048 + s0 + r0] = vch;
      }
      __syncthreads();
    }
  }
}

// ---------------- causal flash attention v8 ----------------
// grid (32, 8): blockIdx.x = bh, blockIdx.y = xb. Linear block id =
// bh + 32*xb -> XCD = bh % 8: ALL 8 blocks of one bh land on the same XCD,
// so its K/V (512 KB) stays L2-resident (4 bh x 512 KB = 2 MB / 4 MB L2).
__global__ __launch_bounds__(512) void flash_kernel(
    const u16* __restrict__ Q, const u16* __restrict__ Kg,
    const u16* __restrict__ Vt, u16* __restrict__ O,
    u16* __restrict__ accP, float* __restrict__ mP, float* __restrict__ lP) {
  constexpr int S = 2048, D = 1024, DH = 64;
  __shared__ u16 Ks[3][4096];  // [key][feat], XOR-swizzled 16B chunks
  __shared__ u16 Vs[3][4096];  // [d][key]
  __shared__ u16 Ps[8][2048];  // per-wave 32q x 64key
  const int tid = threadIdx.x;
  const int w = tid >> 6, lane = tid & 63;
  const int l15 = lane & 15, l4 = lane >> 4;
  const int bh = blockIdx.x, b = bh >> 4, h = bh & 15;
  const int xb = blockIdx.y;
  const int p = xb >> 1, seg = xb & 1;
  const int p1len = seg ? 0 : 4 * p + 4;
  const int kvoff = seg ? (14 - 4 * p) : 0;
  const int TA = seg ? (7 - p) : p;
  const int TB = 7 - p;
  const int qbA_keep = TA * 256 + w * 32;  // for the mid-loop final flush

  const u16* Kbh = Kg + (size_t)b * S * D + h * DH;
  const u16* Vbh = Vt + (size_t)bh * DH * S;

  const int srow = tid >> 3;
  const int scol = ((tid & 7) ^ (srow & 7)) * 8;
  const int sw = l15 & 7;

  // Q fragments: working set qf (phase A) and preloaded qfB (phase B, seg0)
  bf16x8 qf[2][2], qfB[2][2];
#pragma unroll
  for (int c = 0; c < 2; ++c) {
    const u16* qp =
        Q + (size_t)(b * S + qbA_keep + c * 16 + l15) * D + h * DH + l4 * 8;
    qf[c][0] = *(const bf16x8*)qp;
    qf[c][1] = *(const bf16x8*)(qp + 32);
    qfB[c][0] = qf[c][0];
    qfB[c][1] = qf[c][1];
  }
  if (!seg) {
    const int qbB = TB * 256 + w * 32;
#pragma unroll
    for (int c = 0; c < 2; ++c) {
      const u16* qp =
          Q + (size_t)(b * S + qbB + c * 16 + l15) * D + h * DH + l4 * 8;
      qfB[c][0] = *(const bf16x8*)qp;
      qfB[c][1] = *(const bf16x8*)(qp + 32);
    }
  }

  f32x4 acc_o[2][4] = {};
  float m_run[2] = {-3e38f, -3e38f};
  float l_run[2] = {0.f, 0.f};

  int qb = qbA_keep;                 // current wave q base
  int qt64w = TA * 4 + (w >> 1);     // current wave diag 64-tile

  auto kv_of = [&](int j) { return (j < p1len) ? j : (j - p1len + kvoff); };
  auto stage = [&](int kv, int buf) {
    async_ld16(Kbh + (size_t)(kv * 64 + srow) * D + scol, &Ks[buf][w * 512]);
    async_ld16(Vbh + (size_t)srow * S + kv * 64 + scol, &Vs[buf][w * 512]);
  };

  stage(kv_of(0), 0);
  stage(kv_of(1), 1);

  constexpr int NST = 18;
  for (int j = 0; j < NST; ++j) {
    if (j == NST - 1)
      asm volatile("s_waitcnt vmcnt(0)\ns_barrier" ::: "memory");
    else
      asm volatile("s_waitcnt vmcnt(2)\ns_barrier" ::: "memory");
    __builtin_amdgcn_sched_barrier(0);
    if (j + 2 < NST) stage(kv_of(j + 2), (j + 2) % 3);

    if (seg == 0 && j == p1len) {
      // ---- flush FINAL output for tile p, reset for tile 7-p ----
      float lt[2], lq[2][4];
#pragma unroll
      for (int c = 0; c < 2; ++c) {
        float t = l_run[c];
        t += __shfl_xor(t, 16);
        t += __shfl_xor(t, 32);
        lt[c] = t;
#pragma unroll
        for (int r = 0; r < 4; ++r) lq[c][r] = __shfl(lt[c], l4 * 4 + r, 64);
      }
#pragma unroll
      for (int c = 0; c < 2; ++c)
#pragma unroll
        for (int db = 0; db < 4; ++db)
#pragma unroll
          for (int r = 0; r < 4; ++r) {
            const int row = c * 16 + l4 * 4 + r;
            const int col = db * 16 + l15;
            Ps[w][row * 64 + (col ^ ((row & 7) << 3))] =
                f2bf(acc_o[c][db][r] / lq[c][r]);
          }
      asm volatile("s_waitcnt lgkmcnt(0)" ::: "memory");
#pragma unroll
      for (int j4 = 0; j4 < 4; ++j4) {
        const int cid = j4 * 64 + lane;
        const int row = cid >> 3, c8 = cid & 7;
        const u16x8 vch =
            *(const u16x8*)&Ps[w][row * 64 + ((c8 ^ (row & 7)) * 8)];
        *(u16x8*)&O[(size_t)(b * S + qbA_keep + row) * D + h * DH + c8 * 8] =
            vch;
      }
      // reset state for phase B
#pragma unroll
      for (int c = 0; c < 2; ++c) {
        qf[c][0] = qfB[c][0];
        qf[c][1] = qfB[c][1];
        m_run[c] = -3e38f;
        l_run[c] = 0.f;
#pragma unroll
        for (int db = 0; db < 4; ++db) acc_o[c][db] = f32x4{0.f, 0.f, 0.f, 0.f};
      }
      qb = TB * 256 + w * 32;
      qt64w = TB * 4 + (w >> 1);
    }

    const int it = kv_of(j);
    const int buf = j % 3;
    if (it <= qt64w) {
      // ---- S^T = K Q^T (K reads shared by both q fragments) ----
      f32x4 accs[2][4] = {};
      __builtin_amdgcn_s_setprio(1);
#pragma unroll
      for (int cb = 0; cb < 4; ++cb) {
        const int row = cb * 16 + l15;
        const bf16x8 kf0 = *(const bf16x8*)&Ks[buf][row * 64 + ((l4 ^ sw) * 8)];
        const bf16x8 kf1 =
            *(const bf16x8*)&Ks[buf][row * 64 + (((l4 + 4) ^ sw) * 8)];
#pragma unroll
        for (int c = 0; c < 2; ++c) {
          accs[c][cb] = __builtin_amdgcn_mfma_f32_16x16x32_bf16(
              kf0, qf[c][0], accs[c][cb], 0, 0, 0);
          accs[c][cb] = __builtin_amdgcn_mfma_f32_16x16x32_bf16(
              kf1, qf[c][1], accs[c][cb], 0, 0, 0);
        }
      }
      __builtin_amdgcn_s_setprio(0);
      // ---- hoisted V reads (P-independent; latency hides under softmax) ----
      bf16x8 vf0[4], vf1[4];
#pragma unroll
      for (int db = 0; db < 4; ++db) {
        const int row = db * 16 + l15;
        vf0[db] = *(const bf16x8*)&Vs[buf][row * 64 + ((l4 ^ sw) * 8)];
        vf1[db] = *(const bf16x8*)&Vs[buf][row * 64 + (((l4 + 4) ^ sw) * 8)];
      }
      // ---- mask (diag) + local max ----
      float mx[2] = {-3e38f, -3e38f};
      if (it == qt64w) {
#pragma unroll
        for (int c = 0; c < 2; ++c)
#pragma unroll
          for (int cb = 0; cb < 4; ++cb)
#pragma unroll
            for (int r = 0; r < 4; ++r) {
              float s_ = accs[c][cb][r];
              if (it * 64 + cb * 16 + l4 * 4 + r > qb + c * 16 + l15)
                s_ = -3e38f;
              accs[c][cb][r] = s_;
              mx[c] = fmaxf(mx[c], s_);
            }
      } else {
#pragma unroll
        for (int c = 0; c < 2; ++c)
#pragma unroll
          for (int cb = 0; cb < 4; ++cb)
#pragma unroll
            for (int r = 0; r < 4; ++r) mx[c] = fmaxf(mx[c], accs[c][cb][r]);
      }
      // ---- defer-max: rescale only when max grew > 8 (log2 domain) ----
      if (!__all(fmaxf(mx[0] - m_run[0], mx[1] - m_run[1]) <= 8.0f)) {
#pragma unroll
        for (int c = 0; c < 2; ++c) {
          float m = mx[c];
          m = fmaxf(m, __shfl_xor(m, 16));
          m = fmaxf(m, __shfl_xor(m, 32));
          const float mn = fmaxf(m_run[c], m);
          const float corr = __builtin_amdgcn_exp2f(m_run[c] - mn);
          m_run[c] = mn;
          float cq[4];
#pragma unroll
          for (int r = 0; r < 4; ++r) cq[r] = __shfl(corr, l4 * 4 + r, 64);
#pragma unroll
          for (int db = 0; db < 4; ++db)
#pragma unroll
            for (int r = 0; r < 4; ++r) acc_o[c][db][r] *= cq[r];
          l_run[c] *= corr;
        }
      }
#pragma unroll
      for (int c = 0; c < 2; ++c) {
        float rs = 0.f;
#pragma unroll
        for (int cb = 0; cb < 4; ++cb)
#pragma unroll
          for (int r = 0; r < 4; ++r) {
            const float pv = __builtin_amdgcn_exp2f(accs[c][cb][r] - m_run[c]);
            accs[c][cb][r] = pv;
            rs += pv;
          }
        l_run[c] += rs;  // per-lane partial; reduced at flush/epilogue
      }
      // ---- pack P (both fragments) -> swizzled per-wave LDS ----
#pragma unroll
      for (int c = 0; c < 2; ++c)
#pragma unroll
        for (int cb = 0; cb < 4; ++cb) {
          bf16x4 pk = {(bf16_t)accs[c][cb][0], (bf16_t)accs[c][cb][1],
                       (bf16_t)accs[c][cb][2], (bf16_t)accs[c][cb][3]};
          const int chunk = (2 * cb + (l4 >> 1)) ^ sw;
          *(bf16x4*)&Ps[w][(c * 16 + l15) * 64 + chunk * 8 + (l4 & 1) * 4] = pk;
        }
      asm volatile("s_waitcnt lgkmcnt(0)" ::: "memory");
      bf16x8 pa[2][2];
#pragma unroll
      for (int c = 0; c < 2; ++c)
#pragma unroll
        for (int mf = 0; mf < 2; ++mf) {
          const int chunk = (mf * 4 + l4) ^ sw;
          pa[c][mf] =
              *(const bf16x8*)&Ps[w][(c * 16 + l15) * 64 + chunk * 8];
        }
      // ---- O += P V ----
      __builtin_amdgcn_s_setprio(1);
#pragma unroll
      for (int db = 0; db < 4; ++db) {
#pragma unroll
        for (int c = 0; c < 2; ++c) {
          acc_o[c][db] = __builtin_amdgcn_mfma_f32_16x16x32_bf16(
              pa[c][0], vf0[db], acc_o[c][db], 0, 0, 0);
          acc_o[c][db] = __builtin_amdgcn_mfma_f32_16x16x32_bf16(
              pa[c][1], vf1[db], acc_o[c][db], 0, 0, 0);
        }
      }
      __builtin_amdgcn_s_setprio(0);
    }
  }

  // ---- epilogue: PARTIAL write for tile 7-p (both segs) ----
  float lt[2];
#pragma unroll
  for (int c = 0; c < 2; ++c) {
    float t = l_run[c];
    t += __shfl_xor(t, 16);
    t += __shfl_xor(t, 32);
    lt[c] = t;
  }
#pragma unroll
  for (int c = 0; c < 2; ++c)
#pragma unroll
    for (int db = 0; db < 4; ++db)
#pragma unroll
      for (int r = 0; r < 4; ++r) {
        const int row = c * 16 + l4 * 4 + r;
        const int col = db * 16 + l15;
        Ps[w][row * 64 + (col ^ ((row & 7) << 3))] = f2bf(acc_o[c][db][r]);
      }
  asm volatile("s_waitcnt lgkmcnt(0)" ::: "memory");
  const size_t base =
      (size_t)seg * 32768 + (size_t)bh * 1024 + (TB * 256 + w * 32 - 1024);
#pragma unroll
  for (int j4 = 0; j4 < 4; ++j4) {
    const int cid = j4 * 64 + lane;
    const int row = cid >> 3, c8 = cid & 7;
    const u16x8 vch = *(const u16x8*)&Ps[w][row * 64 + ((c8 ^ (row & 7)) * 8)];
    *(u16x8*)&accP[(base + row) * 64 + c8 * 8] = vch;
  }
  if (l4 == 0) {
#pragma unroll
    for (int c = 0; c < 2; ++c) {
      mP[base + c * 16 + l15] = m_run[c];
      lP[base + c * 16 + l15] = lt[c];
    }
  }
}

// ---------------- combine split partials ----------------
__global__ __launch_bounds__(256) void combine_kernel(
    const u16* __restrict__ accP, const float* __restrict__ mP,
    const float* __restrict__ lP, u16* __restrict__ O) {
  const int id = blockIdx.x * 256 + threadIdx.x;  // 262144 tasks
  const int row = id >> 3;                        // 0..32767
  const int c0 = (id & 7) * 8;
  const float m0 = mP[row], m1 = mP[32768 + row];
  const float l0 = lP[row], l1 = lP[32768 + row];
  const float M = fmaxf(m0, m1);
  const float e0 = __builtin_amdgcn_exp2f(m0 - M);
  const float e1 = __builtin_amdgcn_exp2f(m1 - M);
  const float inv = 1.f / (l0 * e0 + l1 * e1);
  const bf16_t* aP = (const bf16_t*)accP;
  const bf16x8 a0 = *(const bf16x8*)&aP[(size_t)row * 64 + c0];
  const bf16x8 a1 = *(const bf16x8*)&aP[(size_t)(32768 + row) * 64 + c0];
  const int bh = row >> 10, s = 1024 + (row & 1023);
  const int b = bh >> 4, h = bh & 15;
  bf16_t* out = (bf16_t*)O + (size_t)(b * 2048 + s) * 1024 + h * 64 + c0;
  bf16x8 o;
#pragma unroll
  for (int j = 0; j < 8; ++j)
    o[j] = (bf16_t)(((float)a0[j] * e0 + (float)a1[j] * e1) * inv);
  *(bf16x8*)out = o;
}

// ---------------- launch ----------------
extern "C" void kernel_launch(void* const* d_in, const int* in_sizes, int n_in,
                              void* d_out, int out_size, void* d_ws, size_t ws_size,
                              hipStream_t stream) {
  (void)in_sizes; (void)n_in; (void)out_size;
  const float* x   = (const float*)d_in[0];
  const float* wts = (const float*)d_in[1];
  const float* Wq  = (const float*)d_in[2];
  const float* bq  = (const float*)d_in[3];
  const float* Wk  = (const float*)d_in[4];
  const float* bk  = (const float*)d_in[5];
  const float* Wv  = (const float*)d_in[6];
  const float* bv  = (const float*)d_in[7];
  const float* Wo  = (const float*)d_in[8];
  const float* bo  = (const float*)d_in[9];
  float* out = (float*)d_out;

  if (ws_size < 58724352) return;  // need ~56 MB scratch

  char* ws = (char*)d_ws;
  u16* xbf  = (u16*)(ws + 0);          // [4096,1024] bf16 (reused as accP later)
  u16* qbf  = (u16*)(ws + 8388608);
  u16* kbf  = (u16*)(ws + 16777216);
  u16* vt   = (u16*)(ws + 33554432);   // [B,H,DH,S] bf16
  u16* attn = (u16*)(ws + 41943040);   // [4096,1024] bf16
  u16* wqkv = (u16*)(ws + 50331648);   // [3072,1024] bf16 (reused as mP/lP)
  u16* wob  = (u16*)(ws + 56623104);   // Weff bf16
  float* beff = (float*)(ws + 58720256);

  // overlays (dead after gemm_qkv):
  u16* accP = xbf;                       // 2 x 32768 x 64 bf16 = 8 MB
  float* mP = (float*)(ws + 50331648);   // 2 x 32768 f32
  float* lP = mP + 65536;

  prep_kernel<<<2048, 256, 0, stream>>>(x, Wq, Wk, Wv, wts, Wo, bo,
                                        xbf, wqkv, wob, beff);
  gemm_qkv_kernel<<<dim3(12, 16), 512, 0, stream>>>(xbf, wqkv, bq, bk, bv,
                                                    qbf, kbf, vt);
  flash_kernel<<<dim3(32, 8), 512, 0, stream>>>(qbf, kbf, vt, attn,
                                                accP, mP, lP);
  combine_kernel<<<1024, 256, 0, stream>>>(accP, mP, lP, attn);
  gemm_bt_kernel<<<dim3(32, 8), 256, 0, stream>>>(
      attn, wob, beff, out, 4096, 1024, 1024);
}